// Round 10
// baseline (79.585 us; speedup 1.0000x reference)
//
#include <hip/hip_runtime.h>
#include <math.h>

#define NFRAMES 16384
#define NJOINTS 22
#define NPATHS  5
#define NPAIRS  (NPATHS * NPATHS)
#define NSEG    16      // segments per motion: 3+3+4+3+3
#define FSTR    (NJOINTS * 3)   // 66 floats per frame per motion
#define OPB     13      // outputs per block
#define LFR     16      // local frames per block (OPB + 3 halo)
#define GLS     26      // LDS gli row stride (floats)

typedef float v2f __attribute__((ext_vector_type(2)));

// Per-segment float offsets (joint*3) into a frame: {start, end}.
// path0 (2,5)(5,8)(8,11); path1 (1,4)(4,7)(7,10);
// path2 (3,6)(6,9)(9,12)(12,15); path3 (14,17)(17,19)(19,21);
// path4 (13,16)(16,18)(18,20).
__constant__ int2 c_seg[NSEG] = {
    {6,15},{15,24},{24,33},
    {3,12},{12,21},{21,30},
    {9,18},{18,27},{27,36},{36,45},
    {42,51},{51,57},{57,63},
    {39,48},{48,54},{54,60}
};
__constant__ int c_pstart[NPATHS] = {0, 3, 6, 10, 13};
__constant__ int c_plen[NPATHS]   = {3, 3, 4, 3, 3};

// Packed 2-frame 3-vector: .x/.y/.z are v2f holding {frameA, frameB}.
struct V3 { v2f x, y, z; };
__device__ __forceinline__ V3 vsub(V3 a, V3 b) { V3 r; r.x=a.x-b.x; r.y=a.y-b.y; r.z=a.z-b.z; return r; }
__device__ __forceinline__ v2f vdot(V3 a, V3 b) { return a.x*b.x + a.y*b.y + a.z*b.z; }
__device__ __forceinline__ V3 vcross(V3 a, V3 b) {
    V3 r;
    r.x = a.y*b.z - a.z*b.y;
    r.y = a.z*b.x - a.x*b.z;
    r.z = a.x*b.y - a.y*b.x;
    return r;
}

// asin via A&S 4.4.45 (degree-3): acos(a)=sqrt(1-a)*poly(a), |eps|<=6.7e-5 rad.
__device__ __forceinline__ v2f vfast_asin(v2f x) {
    v2f a = __builtin_elementwise_max(x, -x);   // |x|
    v2f p = a * -0.0187293f + 0.0742610f;
    p = a * p + -0.2121144f;
    p = a * p + 1.5707288f;
    v2f s;
    s.x = __builtin_amdgcn_sqrtf(1.0f - a.x);
    s.y = __builtin_amdgcn_sqrtf(1.0f - a.y);
    v2f r = 1.5707963268f - s * p;
    r.x = (x.x < 0.0f) ? -r.x : r.x;
    r.y = (x.y < 0.0f) ? -r.y : r.y;
    return r;
}

// asin(clamp(d / sqrt(ma*mb))) with jnp safe-normalize semantics
// (zero-norm face -> normalized vec = 0 -> dot 0 -> asin 0)
__device__ __forceinline__ v2f vasin_term(v2f d, v2f ma, v2f mb) {
    v2f m = ma * mb;
    v2f rs;
    rs.x = __builtin_amdgcn_rsqf(m.x);
    rs.y = __builtin_amdgcn_rsqf(m.y);
    v2f one = 1.0f, mone = -1.0f;
    v2f x = __builtin_elementwise_min(one, __builtin_elementwise_max(mone, d * rs));
    v2f r = vfast_asin(x);
    r.x = (ma.x > 0.0f && mb.x > 0.0f) ? r.x : 0.0f;
    r.y = (ma.y > 0.0f && mb.y > 0.0f) ? r.y : 0.0f;
    return r;
}

__device__ __forceinline__ v2f shfl_xor_v2(v2f v, int mask, int width) {
    v2f r;
    r.x = __shfl_xor(v.x, mask, width);
    r.y = __shfl_xor(v.y, mask, width);
    return r;
}

// One block (512 threads = 8 waves) per 13 OUTPUT frames. Block b covers
// local frames lf = 0..15 mapped to global f = 13b - 1 + lf (1 left + 2
// right halo, clamped at the ends); wave w owns the packed frame pair
// (lf = 2w, 2w+1) end-to-end as in R9 (private LDS staging, 4 packed GLI
// terms per lane, packed bbox butterfly, 25-lane bin-reduce). gli and ov
// stay in LDS; after one barrier, half-wave h (h<13) computes
// out[13b + h] = max_j |gli[lf+2][j]*mask1 - gli[lf+1][j]*mask0| via a
// width-32 max butterfly. No global round-trip, single kernel launch.
__global__ __launch_bounds__(512) void k_fused(const float* __restrict__ m1,
                                               const float* __restrict__ m2,
                                               float* __restrict__ out) {
    __shared__ v2f sF[8][2 * FSTR];   // [wave][motion*66+coord] x {frA, frB}
    __shared__ v2f sT[8][257];        // [wave][term]; [256] = 0 pad
    __shared__ float gl[LFR * GLS];   // [local frame][pair], stride 26
    __shared__ int ovl[LFR];          // dilation source flags

    int t = threadIdx.x;
    int w = t >> 6;
    int l = t & 63;
    int s = (int)blockIdx.x * OPB - 1;       // global frame of local frame 0
    int fA = s + 2 * w;
    int fB = fA + 1;
    int fAc = fA < 0 ? 0 : (fA > NFRAMES - 1 ? NFRAMES - 1 : fA);
    int fBc = fB < 0 ? 0 : (fB > NFRAMES - 1 ? NFRAMES - 1 : fB);

    v2f* sFw = sF[w];
    float* sFf = (float*)sFw;

    const float* aA = m1 + (size_t)fAc * FSTR;
    const float* aB = m1 + (size_t)fBc * FSTR;
    const float* bA = m2 + (size_t)fAc * FSTR;
    const float* bB = m2 + (size_t)fBc * FSTR;

    // Stage both motions' frame pair into [coord]{frA,frB} (stride-2 writes:
    // 2-way LDS aliasing is free). Lanes cover coords 0..63; l<2 covers 64,65.
    {
        sFf[2 * l]     = aA[l];
        sFf[2 * l + 1] = aB[l];
        sFf[2 * (FSTR + l)]     = bA[l];
        sFf[2 * (FSTR + l) + 1] = bB[l];
        if (l < FSTR - 64) {
            int c = l + 64;
            sFf[2 * c]     = aA[c];
            sFf[2 * c + 1] = aB[c];
            sFf[2 * (FSTR + c)]     = bA[c];
            sFf[2 * (FSTR + c) + 1] = bB[c];
        }
        if (l == 32) sT[w][256] = v2f{0.0f, 0.0f};
    }
    __syncthreads();

    // 4 GLI terms per lane: term index l + 64k -> i = (l>>4)+4k, j = l&15.
    {
        int j = l & 15;
        int i0 = l >> 4;
        int2 o2 = c_seg[j];
        const v2f* B = sFw + FSTR;
        V3 s2; s2.x = B[o2.x]; s2.y = B[o2.x+1]; s2.z = B[o2.x+2];
        V3 e2; e2.x = B[o2.y]; e2.y = B[o2.y+1]; e2.z = B[o2.y+2];
        for (int k = 0; k < 4; k++) {
            int2 o1 = c_seg[i0 + 4 * k];
            V3 s1; s1.x = sFw[o1.x]; s1.y = sFw[o1.x+1]; s1.z = sFw[o1.x+2];
            V3 e1; e1.x = sFw[o1.y]; e1.y = sFw[o1.y+1]; e1.z = sFw[o1.y+2];

            V3 r12 = vsub(e1, s1);
            V3 r13 = vsub(s2, s1);
            V3 r14 = vsub(e2, s1);

            // f0v = r13 x r14, c1 = r12 x r13, c2 = r12 x r14
            // faces: f0v, c2, c2-c1-f0v, -c1; sign = -dot(c2, r13)
            V3 f0v = vcross(r13, r14);
            V3 c1  = vcross(r12, r13);
            V3 c2  = vcross(r12, r14);
            V3 f2  = vsub(vsub(c2, c1), f0v);

            v2f q0 = vdot(f0v, f0v);
            v2f q1 = vdot(c2, c2);
            v2f q2 = vdot(f2, f2);
            v2f q3 = vdot(c1, c1);

            v2f g = vasin_term( vdot(f0v, c2), q0, q1)
                  + vasin_term( vdot(c2, f2),  q1, q2)
                  + vasin_term(-vdot(f2, c1),  q2, q3)
                  + vasin_term(-vdot(c1, f0v), q3, q0);

            v2f sg = -vdot(c2, r13);
            v2f res;
            res.x = (sg.x > 0.0f) ? g.x : -g.x;
            res.y = (sg.y > 0.0f) ? g.y : -g.y;
            sT[w][l + 64 * k] = res;
        }
    }

    // bbox overlap, packed over the frame pair; validity-forced at edges.
    {
        int half = l >> 5;                   // 0: motion1, 1: motion2
        int jj = l & 31;
        if (jj > NJOINTS - 1) jj = NJOINTS - 1;  // pad lanes replicate joint 21
        const v2f* p = sFw + half * FSTR;
        v2f x = p[jj * 3 + 0];
        v2f z = p[jj * 3 + 2];
        v2f xn = x, xx = x, zn = z, zx = z;
#pragma unroll
        for (int k = 1; k < 32; k <<= 1) {
            xn = __builtin_elementwise_min(xn, shfl_xor_v2(xn, k, 32));
            xx = __builtin_elementwise_max(xx, shfl_xor_v2(xx, k, 32));
            zn = __builtin_elementwise_min(zn, shfl_xor_v2(zn, k, 32));
            zx = __builtin_elementwise_max(zx, shfl_xor_v2(zx, k, 32));
        }
        v2f oxn = shfl_xor_v2(xn, 32, 64);
        v2f oxx = shfl_xor_v2(xx, 32, 64);
        v2f ozn = shfl_xor_v2(zn, 32, 64);
        v2f ozx = shfl_xor_v2(zx, 32, 64);
        if (l == 0) {
            bool vx0 = !((xx.x < oxn.x) || (oxx.x < xn.x));
            bool vz0 = !((zx.x < ozn.x) || (ozx.x < zn.x));
            bool vx1 = !((xx.y < oxn.y) || (oxx.y < xn.y));
            bool vz1 = !((zx.y < ozn.y) || (ozx.y < zn.y));
            ovl[2 * w]     = (fA >= 0 && fA < NFRAMES && vx0 && vz0) ? 1 : 0;
            ovl[2 * w + 1] = (fB >= 0 && fB < NFRAMES && vx1 && vz1) ? 1 : 0;
        }
    }
    __syncthreads();

    // Bin-reduce: lanes 0..24 of each wave -> gl rows 2w, 2w+1 (scaled).
    if (l < NPAIRS) {
        int pa = (l * 205) >> 10;   // l/5 for l<25
        int pb = l - pa * 5;        // l%5
        int ia0 = c_pstart[pa], na = c_plen[pa];
        int ib0 = c_pstart[pb], nb = c_plen[pb];
        v2f sum = v2f{0.0f, 0.0f};
#pragma unroll
        for (int ka = 0; ka < 4; ka++) {
#pragma unroll
            for (int kb = 0; kb < 4; kb++) {
                int idx = (ka < na && kb < nb) ? ((ia0 + ka) * 16 + (ib0 + kb)) : 256;
                sum += sT[w][idx];
            }
        }
        sum *= 0.07957747154594767f;  // 1/(4*pi)
        gl[(2 * w) * GLS + l]     = sum.x;
        gl[(2 * w + 1) * GLS + l] = sum.y;
    }
    __syncthreads();

    // Output: half-wave h emits out[13b + h] for h < 13.
    // out[f] = max_j |gl[lf+1][j]*mask1 - gl[lf][j]*mask0|, lf = h+1;
    // mask0 = ovl[lf-1]|ovl[lf]|ovl[lf+1], mask1 = ovl[lf]|ovl[lf+1]|ovl[lf+2].
    {
        int h = t >> 5;              // 0..15
        int j = t & 31;
        int f = (int)blockIdx.x * OPB + h;
        if (h < OPB && f <= NFRAMES - 2) {
            int lf = h + 1;
            int mm0 = ovl[lf - 1] | ovl[lf] | ovl[lf + 1];
            int mm1 = ovl[lf] | ovl[lf + 1] | ovl[lf + 2];
            float ma = mm0 ? 1.0f : 0.0f;
            float mb = mm1 ? 1.0f : 0.0f;
            float v = 0.0f;
            if (j < NPAIRS)
                v = fabsf(gl[(lf + 1) * GLS + j] * mb - gl[lf * GLS + j] * ma);
#pragma unroll
            for (int k = 1; k < 32; k <<= 1)
                v = fmaxf(v, __shfl_xor(v, k, 32));
            if (j == 0) out[f] = v;
        }
    }
}

extern "C" void kernel_launch(void* const* d_in, const int* in_sizes, int n_in,
                              void* d_out, int out_size, void* d_ws, size_t ws_size,
                              hipStream_t stream) {
    const float* m1 = (const float*)d_in[0];
    const float* m2 = (const float*)d_in[1];
    float* out = (float*)d_out;

    int blocks = (NFRAMES - 1 + OPB - 1) / OPB;   // 1261
    k_fused<<<blocks, 512, 0, stream>>>(m1, m2, out);
}